// Round 13
// baseline (216.351 us; speedup 1.0000x reference)
//
#include <hip/hip_runtime.h>

#define M_TOTAL 8192
#define KDIM 1024
#define TASKS 20
#define SBUF 256

typedef __attribute__((ext_vector_type(4))) int i32x4;
typedef __attribute__((ext_vector_type(8))) int i32x8;
typedef __attribute__((ext_vector_type(16))) float f32x16;

__device__ __forceinline__ void gload_lds16(const void* g, char* l) {
  __builtin_amdgcn_global_load_lds((const __attribute__((address_space(1))) void*)g,
                                   (__attribute__((address_space(3))) void*)l, 16, 0, 0);
}

#define FENCE() asm volatile("" ::: "memory")
#define BAR() do { FENCE(); __builtin_amdgcn_s_barrier(); FENCE(); } while (0)
#define LGKM0() asm volatile("s_waitcnt lgkmcnt(0)" ::: "memory")
#define VMC(n) asm volatile("s_waitcnt vmcnt(" #n ")" ::: "memory")
#define SCHED0() __builtin_amdgcn_sched_barrier(0)
// All scale bytes = 0x7F (E8M0 exp 0 -> x1.0): plain fp8 GEMM at MX rate.
#define MFMA_(a, bb, c) \
  (c) = __builtin_amdgcn_mfma_scale_f32_32x32x64_f8f6f4((a), (bb), (c), 0, 0, \
                                                        0, 0x7F7F7F7F, 0, 0x7F7F7F7F)

// One block per row: L2-normalize a 1024-float row of X or W, emit fp8 e4m3
// (RNE via v_cvt_pk_fp8_f32). First 640 blocks also init out[] to -1e30 for
// the atomicMin combine (runs before gemm in stream order).
__global__ __launch_bounds__(256) void norm_rows_kernel(const float* __restrict__ X,
                                                        const float* __restrict__ W,
                                                        unsigned int* __restrict__ Xq,
                                                        unsigned int* __restrict__ Wq,
                                                        float* __restrict__ out) {
  const int row = blockIdx.x;
  const int tid = threadIdx.x;
  if (row < (M_TOTAL * TASKS) / 256) out[row * 256 + tid] = -1e30f;
  const float* in;
  unsigned int* outp;
  int r;
  if (row < M_TOTAL) { in = X; outp = Xq; r = row; }
  else               { in = W; outp = Wq; r = row - M_TOTAL; }
  const float4 v = ((const float4*)(in + (size_t)r * KDIM))[tid];
  float s = v.x * v.x + v.y * v.y + v.z * v.z + v.w * v.w;
#pragma unroll
  for (int off = 32; off >= 1; off >>= 1) s += __shfl_xor(s, off, 64);
  __shared__ float part[4];
  if ((tid & 63) == 0) part[tid >> 6] = s;
  __syncthreads();
  s = part[0] + part[1] + part[2] + part[3];
  const float sc = rsqrtf(s);
  int pk = __builtin_amdgcn_cvt_pk_fp8_f32(v.x * sc, v.y * sc, 0, false);
  pk = __builtin_amdgcn_cvt_pk_fp8_f32(v.z * sc, v.w * sc, pk, true);
  outp[(size_t)r * (KDIM / 4) + tid] = (unsigned int)pk;
}

// 128(M) x 128(N) x BK=128 fp8-MX tile, 32x32x64 MFMA shape. 256 thr = 4 waves
// (2M x 2N), wave tile 64x64 = 2x2 32x32 tiles, acc[2][2] f32x16 (64 AGPR).
// *** r12 fix: the 16x16x128 shape kept aF[4]+bF[4]=64 frag regs live across
// the whole tile -> arch 244 + 64 agpr = 308 -> 1 wave/SIMD (occ 10.9%).
// 32x32x64 splits each K-tile into 2 k-steps of {4 frag loads (32 regs),
// 4 MFMAs} -> frags die between steps -> arch ~110 <= 128 -> (256,2) fits
// with 2 waves/SIMD, 2 blocks/CU, no spill (r11's (256,2) spill was the
// 16x16-shape's 180-reg arch need vs the 128 pin). ***
// Operand layout (32-wide analog of r12's HW-validated 16x16x128 mapping):
// A row = lane&31, k = (lane>>5)*32 + e; B col = lane&31, same k. C/D:
// col=lane&31, row=(reg&3)+8*(reg>>2)+4*(lane>>5) (m74/m101, shape-determined).
// LDS per buf (32 KB at B_*32768): A [0,16K) 128-B rows, B [16K,32K).
// Swizzle: granule slot' = c16 ^ (row&7); k-step1 granules = step0 ^ 4 ->
// byte offset ^ 64. Stage dest linear, source inverse-permuted (rule #21).
// 8 K-tiles, 2-barrier KTILE, counted VMC(8) 2-deep ledger; STG after the
// tile's last frag read (LGKM0+BAR protects the buffer being overwritten).
__global__ __launch_bounds__(256, 2) void gemm_min_kernel(const unsigned char* __restrict__ Xq,
                                                          const unsigned char* __restrict__ Wq,
                                                          float* __restrict__ out) {
  __shared__ __align__(16) char sm[66560];

  const int tid = threadIdx.x;
  const int lane = tid & 63;
  const int w = tid >> 6, wr = w >> 1, wc = w & 1;
  const int l31 = lane & 31, l2 = lane >> 5;

  // XCD swizzle: 2560 blocks; xcd owns an 8-mblk stripe, mblk fastest, nblk slow.
  const int o = blockIdx.x;
  const int xcd = o & 7, i = o >> 3;        // i in [0,320)
  const int nblk = i >> 3;                   // 0..39
  const int mblk = xcd * 8 + (i & 7);        // 0..63
  const int rowBase = mblk * 128;
  const int col0 = nblk * 128;
  const int task = nblk >> 1;

  // staging source decode (inverse of slot' = c16 ^ (row&7)); chunk ii adds
  // 32 rows (ii*32*KDIM source, ii*4096 linear dest) — c16 chunk-invariant.
  const int c16 = (tid & 7) ^ ((tid >> 3) & 7);
  const unsigned char* pA = Xq + (size_t)(rowBase + (tid >> 3)) * KDIM + c16 * 16;
  const unsigned char* pB = Wq + (size_t)(col0 + (tid >> 3)) * KDIM + c16 * 16;

  // frag read bases: row = (wr|wc)*64 + mi*32 + l31 (row&7 = lane&7);
  // k-step0 granules l2*2, l2*2+1 -> phys (l2*2)^(lane&7), ^1 via off^16;
  // k-step1: ^4 via off^64.
  const int slot = ((l2 * 2) ^ (lane & 7)) * 16;
  const int aBase = (wr * 64 + l31) * 128 + slot;
  const int bBase = 16384 + (wc * 64 + l31) * 128 + slot;

  f32x16 acc[2][2] = {};

  // 8 loads/thread/K-tile into buf B_: A chunks 0..3 (128 rows), B chunks 0..3
#define STG(B_, kB) do { \
    _Pragma("unroll") for (int ii = 0; ii < 4; ++ii) { \
      gload_lds16(pA + (size_t)ii * 32 * KDIM + (kB), sm + (B_) * 32768 + ii * 4096 + tid * 16); \
      gload_lds16(pB + (size_t)ii * 32 * KDIM + (kB), sm + (B_) * 32768 + 16384 + ii * 4096 + tid * 16); \
    } } while (0)

  // well-defined 32-byte fragment load: two i32x4 LDS reads + shufflevector
#define LD32(dst, base_, off_) do { \
    i32x4 lo_ = *(const i32x4*)((base_) + (off_)); \
    i32x4 hi_ = *(const i32x4*)((base_) + ((off_) ^ 16)); \
    (dst) = __builtin_shufflevector(lo_, hi_, 0, 1, 2, 3, 4, 5, 6, 7); \
  } while (0)

  // prologue: tile0 -> buf0, tile1 -> buf1; VMC(8) -> tile0 resident
  STG(0, 0);
  STG(1, 128);
  VMC(8); SCHED0();
  BAR();

  // Per K-tile: {ks0: 4 frag loads + 4 MFMA; ks1 (off^64): same; LGKM0; BAR;
  //              STG t+2 -> own buf; VMC(8) [t+1 resident]; BAR}.
#define KSTEP(base, xorv) do { \
    i32x8 aF[2], bF[2]; \
    LD32(aF[0], base, (aBase) ^ (xorv)); \
    LD32(aF[1], base, (aBase + 4096) ^ (xorv)); \
    LD32(bF[0], base, (bBase) ^ (xorv)); \
    LD32(bF[1], base, (bBase + 4096) ^ (xorv)); \
    __builtin_amdgcn_s_setprio(1); \
    MFMA_(aF[0], bF[0], acc[0][0]); MFMA_(aF[0], bF[1], acc[0][1]); \
    MFMA_(aF[1], bF[0], acc[1][0]); MFMA_(aF[1], bF[1], acc[1][1]); \
    __builtin_amdgcn_s_setprio(0); \
  } while (0)

#define KTILE(B_, kt) do { \
    const char* base = sm + (B_) * 32768; \
    KSTEP(base, 0); \
    KSTEP(base, 64); \
    LGKM0(); SCHED0(); \
    BAR(); \
    { const int kB = ((kt) + 2 < 8) ? ((kt) + 2) * 128 : 0; STG(B_, kB); } \
    VMC(8); SCHED0(); \
    BAR(); \
  } while (0)

  for (int kt = 0; kt < 8; kt += 2) {
    KTILE(0, kt);
    KTILE(1, kt + 1);
  }

  // Drain wrap-garbage stages before reusing LDS / ending the block (r5 race).
  VMC(0); SCHED0();
  BAR();

  // epilogue: per-row max-dot over 2 n-tiles + 32 col-lanes -> red -> atomic.
  float (*red)[2] = (float (*)[2])(sm + 65536);  // outside staging regions
#pragma unroll
  for (int mi = 0; mi < 2; ++mi) {
#pragma unroll
    for (int r = 0; r < 16; ++r) {
      float v = fmaxf(acc[mi][0][r], acc[mi][1][r]);
      v = fmaxf(v, __shfl_xor(v, 1, 64));
      v = fmaxf(v, __shfl_xor(v, 2, 64));
      v = fmaxf(v, __shfl_xor(v, 4, 64));
      v = fmaxf(v, __shfl_xor(v, 8, 64));
      v = fmaxf(v, __shfl_xor(v, 16, 64));
      if (l31 == 0)
        red[wr * 64 + mi * 32 + (r & 3) + 8 * (r >> 2) + 4 * l2][wc] = v;
    }
  }
  BAR();
  if (tid < 128) {
    const float vv = fmaxf(red[tid][0], red[tid][1]);
    const float d = sqrtf(fmaxf(2.0f - 2.0f * vv, 1e-12f));
    // all published values negative: uint atomicMin == float max == -min dist
    atomicMin((unsigned int*)&out[(size_t)(rowBase + tid) * TASKS + task],
              __float_as_uint(-d));
  }
#undef KTILE
#undef KSTEP
#undef LD32
#undef STG
}

extern "C" void kernel_launch(void* const* d_in, const int* in_sizes, int n_in,
                              void* d_out, int out_size, void* d_ws, size_t ws_size,
                              hipStream_t stream) {
  const float* X = (const float*)d_in[0];   // (8192, 1024) fp32
  const float* W = (const float*)d_in[1];   // (5120, 1024) fp32
  float* out = (float*)d_out;               // (8192, 20) fp32

  unsigned char* Xq = (unsigned char*)d_ws;                          // 8.4 MB fp8
  unsigned char* Wq = Xq + (size_t)M_TOTAL * KDIM;                   // 5.2 MB fp8

  norm_rows_kernel<<<M_TOTAL + TASKS * SBUF, 256, 0, stream>>>(
      X, W, (unsigned int*)Xq, (unsigned int*)Wq, out);
  gemm_min_kernel<<<2560, 256, 0, stream>>>(Xq, Wq, out);
}

// Round 14
// 131.443 us; speedup vs baseline: 1.6460x; 1.6460x over previous
//
#include <hip/hip_runtime.h>

#define M_TOTAL 8192
#define KDIM 1024
#define TASKS 20
#define SBUF 256

typedef __attribute__((ext_vector_type(4))) int i32x4;
typedef __attribute__((ext_vector_type(8))) int i32x8;
typedef __attribute__((ext_vector_type(16))) float f32x16;

__device__ __forceinline__ void gload_lds16(const void* g, char* l) {
  __builtin_amdgcn_global_load_lds((const __attribute__((address_space(1))) void*)g,
                                   (__attribute__((address_space(3))) void*)l, 16, 0, 0);
}

#define FENCE() asm volatile("" ::: "memory")
#define BAR() do { FENCE(); __builtin_amdgcn_s_barrier(); FENCE(); } while (0)
#define LGKM0() asm volatile("s_waitcnt lgkmcnt(0)" ::: "memory")
#define VMC(n) asm volatile("s_waitcnt vmcnt(" #n ")" ::: "memory")
#define SCHED0() __builtin_amdgcn_sched_barrier(0)
// All scale bytes = 0x7F (E8M0 exp 0 -> x1.0): plain fp8 GEMM at MX rate.
#define MFMA_(a, bb, c) \
  (c) = __builtin_amdgcn_mfma_scale_f32_32x32x64_f8f6f4((a), (bb), (c), 0, 0, \
                                                        0, 0x7F7F7F7F, 0, 0x7F7F7F7F)

// One block per row: L2-normalize a 1024-float row of X or W, emit fp8 e4m3
// (RNE via v_cvt_pk_fp8_f32). First 640 blocks also init out[] to -1e30 for
// the atomicMin combine (runs before gemm in stream order).
__global__ __launch_bounds__(256) void norm_rows_kernel(const float* __restrict__ X,
                                                        const float* __restrict__ W,
                                                        unsigned int* __restrict__ Xq,
                                                        unsigned int* __restrict__ Wq,
                                                        float* __restrict__ out) {
  const int row = blockIdx.x;
  const int tid = threadIdx.x;
  if (row < (M_TOTAL * TASKS) / 256) out[row * 256 + tid] = -1e30f;
  const float* in;
  unsigned int* outp;
  int r;
  if (row < M_TOTAL) { in = X; outp = Xq; r = row; }
  else               { in = W; outp = Wq; r = row - M_TOTAL; }
  const float4 v = ((const float4*)(in + (size_t)r * KDIM))[tid];
  float s = v.x * v.x + v.y * v.y + v.z * v.z + v.w * v.w;
#pragma unroll
  for (int off = 32; off >= 1; off >>= 1) s += __shfl_xor(s, off, 64);
  __shared__ float part[4];
  if ((tid & 63) == 0) part[tid >> 6] = s;
  __syncthreads();
  s = part[0] + part[1] + part[2] + part[3];
  const float sc = rsqrtf(s);
  int pk = __builtin_amdgcn_cvt_pk_fp8_f32(v.x * sc, v.y * sc, 0, false);
  pk = __builtin_amdgcn_cvt_pk_fp8_f32(v.z * sc, v.w * sc, pk, true);
  outp[(size_t)r * (KDIM / 4) + tid] = (unsigned int)pk;
}

// 128(M) x 128(N) x BK=128 fp8-MX tile, 32x32x64 MFMA shape (r13 layouts
// HW-verified: absmax 0.0078). 256 thr = 4 waves (2M x 2N), wave tile 64x64 =
// 2x2 32x32 tiles, acc[2][2] f32x16.
// *** r13 fix: __launch_bounds__(256, 1). The mfma_scale_* forms keep C/D in
// the ARCH VGPR file (r12: VGPR_Count 244, no AGPR split; r11/r13: pinned at
// 128 under (256,2) -> 576-623 MB scratch). True arch demand = 64 acc + 32
// frags + ~60 addressing ~= 160-210; (256,1) lets the allocator take it.
// Occupancy is capped by LDS (66.5 KB -> 2 blocks/CU = 2 waves/SIMD), and
// 2 x ~210 regs = 420 <= 512 per-SIMD pool, so residency is unchanged from
// the bf16 rounds — just without spill at MX rate. ***
// Layouts: A row=lane&31, k=(lane>>5)*32+e; B col=lane&31 same k; C/D
// col=lane&31, row=(reg&3)+8*(reg>>2)+4*(lane>>5) (m74/m101).
// LDS per buf (32 KB at B_*32768): A [0,16K) 128-B rows, B [16K,32K).
// Swizzle: granule slot' = c16 ^ (row&7); k-step1 = step0 ^ 4 -> byte ^ 64.
// Stage dest linear, source inverse-permuted (rule #21). 8 K-tiles,
// 2-barrier KTILE, counted VMC(8) 2-deep ledger.
__global__ __launch_bounds__(256, 1) void gemm_min_kernel(const unsigned char* __restrict__ Xq,
                                                          const unsigned char* __restrict__ Wq,
                                                          float* __restrict__ out) {
  __shared__ __align__(16) char sm[66560];

  const int tid = threadIdx.x;
  const int lane = tid & 63;
  const int w = tid >> 6, wr = w >> 1, wc = w & 1;
  const int l31 = lane & 31, l2 = lane >> 5;

  // XCD swizzle: 2560 blocks; xcd owns an 8-mblk stripe, mblk fastest, nblk slow.
  const int o = blockIdx.x;
  const int xcd = o & 7, i = o >> 3;        // i in [0,320)
  const int nblk = i >> 3;                   // 0..39
  const int mblk = xcd * 8 + (i & 7);        // 0..63
  const int rowBase = mblk * 128;
  const int col0 = nblk * 128;
  const int task = nblk >> 1;

  // staging source decode (inverse of slot' = c16 ^ (row&7)); chunk ii adds
  // 32 rows (ii*32*KDIM source, ii*4096 linear dest) — c16 chunk-invariant.
  const int c16 = (tid & 7) ^ ((tid >> 3) & 7);
  const unsigned char* pA = Xq + (size_t)(rowBase + (tid >> 3)) * KDIM + c16 * 16;
  const unsigned char* pB = Wq + (size_t)(col0 + (tid >> 3)) * KDIM + c16 * 16;

  // frag read bases: row = (wr|wc)*64 + mi*32 + l31 (row&7 = lane&7);
  // k-step0 granules l2*2, l2*2+1 -> phys (l2*2)^(lane&7), ^1 via off^16;
  // k-step1: ^4 via off^64.
  const int slot = ((l2 * 2) ^ (lane & 7)) * 16;
  const int aBase = (wr * 64 + l31) * 128 + slot;
  const int bBase = 16384 + (wc * 64 + l31) * 128 + slot;

  f32x16 acc[2][2] = {};

  // 8 loads/thread/K-tile into buf B_: A chunks 0..3 (128 rows), B chunks 0..3
#define STG(B_, kB) do { \
    _Pragma("unroll") for (int ii = 0; ii < 4; ++ii) { \
      gload_lds16(pA + (size_t)ii * 32 * KDIM + (kB), sm + (B_) * 32768 + ii * 4096 + tid * 16); \
      gload_lds16(pB + (size_t)ii * 32 * KDIM + (kB), sm + (B_) * 32768 + 16384 + ii * 4096 + tid * 16); \
    } } while (0)

  // well-defined 32-byte fragment load: two i32x4 LDS reads + shufflevector
#define LD32(dst, base_, off_) do { \
    i32x4 lo_ = *(const i32x4*)((base_) + (off_)); \
    i32x4 hi_ = *(const i32x4*)((base_) + ((off_) ^ 16)); \
    (dst) = __builtin_shufflevector(lo_, hi_, 0, 1, 2, 3, 4, 5, 6, 7); \
  } while (0)

  // prologue: tile0 -> buf0, tile1 -> buf1; VMC(8) -> tile0 resident
  STG(0, 0);
  STG(1, 128);
  VMC(8); SCHED0();
  BAR();

  // Per K-tile: {ks0: 4 frag loads + 4 MFMA; ks1 (off^64): same; LGKM0; BAR;
  //              STG t+2 -> own buf; VMC(8) [t+1 resident]; BAR}.
#define KSTEP(base, xorv) do { \
    i32x8 aF[2], bF[2]; \
    LD32(aF[0], base, (aBase) ^ (xorv)); \
    LD32(aF[1], base, (aBase + 4096) ^ (xorv)); \
    LD32(bF[0], base, (bBase) ^ (xorv)); \
    LD32(bF[1], base, (bBase + 4096) ^ (xorv)); \
    __builtin_amdgcn_s_setprio(1); \
    MFMA_(aF[0], bF[0], acc[0][0]); MFMA_(aF[0], bF[1], acc[0][1]); \
    MFMA_(aF[1], bF[0], acc[1][0]); MFMA_(aF[1], bF[1], acc[1][1]); \
    __builtin_amdgcn_s_setprio(0); \
  } while (0)

#define KTILE(B_, kt) do { \
    const char* base = sm + (B_) * 32768; \
    KSTEP(base, 0); \
    KSTEP(base, 64); \
    LGKM0(); SCHED0(); \
    BAR(); \
    { const int kB = ((kt) + 2 < 8) ? ((kt) + 2) * 128 : 0; STG(B_, kB); } \
    VMC(8); SCHED0(); \
    BAR(); \
  } while (0)

  for (int kt = 0; kt < 8; kt += 2) {
    KTILE(0, kt);
    KTILE(1, kt + 1);
  }

  // Drain wrap-garbage stages before reusing LDS / ending the block (r5 race).
  VMC(0); SCHED0();
  BAR();

  // epilogue: per-row max-dot over 2 n-tiles + 32 col-lanes -> red -> atomic.
  float (*red)[2] = (float (*)[2])(sm + 65536);  // outside staging regions
#pragma unroll
  for (int mi = 0; mi < 2; ++mi) {
#pragma unroll
    for (int r = 0; r < 16; ++r) {
      float v = fmaxf(acc[mi][0][r], acc[mi][1][r]);
      v = fmaxf(v, __shfl_xor(v, 1, 64));
      v = fmaxf(v, __shfl_xor(v, 2, 64));
      v = fmaxf(v, __shfl_xor(v, 4, 64));
      v = fmaxf(v, __shfl_xor(v, 8, 64));
      v = fmaxf(v, __shfl_xor(v, 16, 64));
      if (l31 == 0)
        red[wr * 64 + mi * 32 + (r & 3) + 8 * (r >> 2) + 4 * l2][wc] = v;
    }
  }
  BAR();
  if (tid < 128) {
    const float vv = fmaxf(red[tid][0], red[tid][1]);
    const float d = sqrtf(fmaxf(2.0f - 2.0f * vv, 1e-12f));
    // all published values negative: uint atomicMin == float max == -min dist
    atomicMin((unsigned int*)&out[(size_t)(rowBase + tid) * TASKS + task],
              __float_as_uint(-d));
  }
#undef KTILE
#undef KSTEP
#undef LD32
#undef STG
}

extern "C" void kernel_launch(void* const* d_in, const int* in_sizes, int n_in,
                              void* d_out, int out_size, void* d_ws, size_t ws_size,
                              hipStream_t stream) {
  const float* X = (const float*)d_in[0];   // (8192, 1024) fp32
  const float* W = (const float*)d_in[1];   // (5120, 1024) fp32
  float* out = (float*)d_out;               // (8192, 20) fp32

  unsigned char* Xq = (unsigned char*)d_ws;                          // 8.4 MB fp8
  unsigned char* Wq = Xq + (size_t)M_TOTAL * KDIM;                   // 5.2 MB fp8

  norm_rows_kernel<<<M_TOTAL + TASKS * SBUF, 256, 0, stream>>>(
      X, W, (unsigned int*)Xq, (unsigned int*)Wq, out);
  gemm_min_kernel<<<2560, 256, 0, stream>>>(Xq, Wq, out);
}